// Round 7
// baseline (93.140 us; speedup 1.0000x reference)
//
#include <hip/hip_runtime.h>
#include <float.h>

#define N_SRC 20000
#define N_TAR 20000
#define TPB 512                    // 8 waves/block
#define SPLITS 8                   // source splits (grid.y)
#define PHASES 2                   // staging phases per split (reuse 40 KB LDS)
#define TILES 40                   // 32-source tiles per phase; 8*2*40*32 = 20480 >= 20000
#define TGRP 79                    // target-strip groups (grid.x); 79*8 strips*32 = 20224 >= 20000
#define NBLK (TGRP * SPLITS)       // 632 blocks total
#define NFIN 40                    // last-40 arrivers run the finalize phase
#define TPERF (N_TAR / NFIN)       // 500 targets per finalizer block

typedef _Float16 half8 __attribute__((ext_vector_type(8)));
typedef float floatx16 __attribute__((ext_vector_type(16)));

// Per-(split,target) partial mins in a device global (NOT the poisoned ws).
// Each 128B line of g_part (32 consecutive floats = one (split,strip) row-set)
// is written by exactly ONE wave -> no cross-XCD line sharing. Visibility to
// the finalizer blocks is established by each block's RELEASE fetch_add on
// g_done (flushes that XCD's dirty L2 lines) + the finalizers' acquire fence.
__device__ float g_part[SPLITS * N_TAR];
__device__ unsigned g_done = 0;    // monotone arrival counter (epoch = /NBLK)

// DPP rotate-min within each 16-lane row (VALU pipe; HW-validated in R4).
#define ROTMIN(v, ctrl) \
    fminf(v, __int_as_float(__builtin_amdgcn_mov_dpp(__float_as_int(v), ctrl, 0xF, 0xF, false)))

// q(t,s) = 0.5||s||^2 - t.s, so 0.5*d2 = 0.5||t||^2 + q.
// One mfma_f32_32x32x16_f16 computes a 32x32 tile of q directly:
//   A row (target t): k0-8 = -t split-f16 cross terms, k9-10 = 1.0
//   B col (source s): k0-8 = s split-f16 terms,        k9-10 = split 0.5||s||^2
// A layout: A[m=lane&31][k=(lane>>5)*8+j]; B[k=(lane>>5)*8+j][n=lane&31];
// C/D: col=lane&31, row=(reg&3)+8*(reg>>2)+4*(lane>>5)  [m74/m101].
//
// R7: single fused dispatch. Main phase identical to R6 (75.8us measured).
// Epilogue: every block does ONE release fetch_add; the last NFIN arrivers
// (guaranteed-resident by definition of "arriver") spin until all NBLK have
// arrived, then finalize disjoint 500-target slices and atomicAdd into out.
// Non-finalizer blocks exit immediately -> slots recycle -> forward progress.
__global__ __launch_bounds__(TPB) void nn_fused(
    const float* __restrict__ src, const float* __restrict__ tar,
    float* __restrict__ out)
{
    if (blockIdx.x == 0 && blockIdx.y == 0 && threadIdx.x == 0) out[0] = 0.f;

    __shared__ alignas(16) _Float16 lds[TILES * 32 * 16];  // 40 KB
    __shared__ int fidx;
    __shared__ float red[8];

    const int tid  = threadIdx.x;
    const int lane = tid & 63;
    const int col  = lane & 31;
    const int hsel = (lane >> 5) & 1;
    const int wave = tid >> 6;

    // ---- build A fragment: this wave's 32 targets ----
    const int strip = blockIdx.x * 8 + wave;
    const int t = min(strip * 32 + col, N_TAR - 1);
    const float tx = tar[t * 3 + 0];
    const float ty = tar[t * 3 + 1];
    const float tz = tar[t * 3 + 2];
    const _Float16 txh = (_Float16)tx, tyh = (_Float16)ty, tzh = (_Float16)tz;
    const _Float16 txl = (_Float16)(tx - (float)txh);
    const _Float16 tyl = (_Float16)(ty - (float)tyh);
    const _Float16 tzl = (_Float16)(tz - (float)tzh);
    half8 a;
    if (hsel == 0)
        a = (half8){-txh, -tyh, -tzh, -txl, -tyl, -tzl, -txh, -tyh};
    else
        a = (half8){-tzh, (_Float16)1.f, (_Float16)1.f, 0, 0, 0, 0, 0};

    floatx16 m;
#pragma unroll
    for (int i = 0; i < 16; ++i) m[i] = FLT_MAX;
    const floatx16 zero = {};  // all-zero accumulator init
    const int foff = col * 16 + hsel * 8;  // linear 1 KB/tile: zero bank conflicts
    const int sbase0 = blockIdx.y * (PHASES * TILES * 32);

    for (int phase = 0; phase < PHASES; ++phase) {
        if (phase) __syncthreads();  // all waves done reading previous phase's LDS

        // ---- stage B fragments for this phase's 1280 sources ----
        const int pbase = sbase0 + phase * (TILES * 32);
        for (int ls = tid; ls < TILES * 32; ls += TPB) {
            const int s = pbase + ls;
            half8 f0 = {0, 0, 0, 0, 0, 0, 0, 0};
            half8 f1 = {0, 0, 0, 0, 0, 0, 0, 0};
            if (s < N_SRC) {
                const float x = src[s * 3 + 0];
                const float y = src[s * 3 + 1];
                const float z = src[s * 3 + 2];
                const _Float16 xh = (_Float16)x, yh = (_Float16)y, zh = (_Float16)z;
                const _Float16 xl = (_Float16)(x - (float)xh);
                const _Float16 yl = (_Float16)(y - (float)yh);
                const _Float16 zl = (_Float16)(z - (float)zh);
                const float nrm = 0.5f * (x * x + y * y + z * z);
                const _Float16 nh = (_Float16)nrm;
                const _Float16 nl = (_Float16)(nrm - (float)nh);
                f0 = (half8){xh, yh, zh, xh, yh, zh, xl, yl};
                f1 = (half8){zl, nh, nl, 0, 0, 0, 0, 0};
            } else {
                f1 = (half8){0, (_Float16)30000.f, 0, 0, 0, 0, 0, 0}; // never the min
            }
            *(half8*)&lds[ls * 16 + 0] = f0;
            *(half8*)&lds[ls * 16 + 8] = f1;
        }

        __syncthreads();

        // ---- scan tiles in pairs: 2 ds_read_b128 + 2 mfma + 16 v_min3 / 2048 pairs ----
#pragma unroll 2
        for (int tp = 0; tp < TILES; tp += 2) {
            const half8 b0 = *(const half8*)&lds[tp * 512 + foff];
            const half8 b1 = *(const half8*)&lds[(tp + 1) * 512 + foff];
            const floatx16 d0 = __builtin_amdgcn_mfma_f32_32x32x16_f16(a, b0, zero, 0, 0, 0);
            const floatx16 d1 = __builtin_amdgcn_mfma_f32_32x32x16_f16(a, b1, zero, 0, 0, 0);
#pragma unroll
            for (int i = 0; i < 16; ++i)
                m[i] = fminf(fminf(d0[i], d1[i]), m[i]);  // -> v_min3_f32
        }
    }

    // ---- min over the 32 columns: 4x DPP row_ror (VALU) + 1 shfl_xor(16) ----
#pragma unroll
    for (int i = 0; i < 16; ++i) {
        float v = m[i];
        v = ROTMIN(v, 0x128);   // row_ror:8
        v = ROTMIN(v, 0x124);   // row_ror:4
        v = ROTMIN(v, 0x122);   // row_ror:2
        v = ROTMIN(v, 0x121);   // row_ror:1
        m[i] = fminf(v, __shfl_xor(v, 16));
    }
    if (col == 0) {
#pragma unroll
        for (int i = 0; i < 16; ++i) {
            const int row = (i & 3) + 8 * (i >> 2) + 4 * hsel;
            const int tt = min(strip * 32 + row, N_TAR - 1);
            g_part[blockIdx.y * N_TAR + tt] = m[i];
        }
    }

    // ---- arrival + last-NFIN finalize ----
    __syncthreads();   // drains vmcnt: all waves' g_part stores are in L2
    if (tid == 0) {
        // release: flush this XCD's dirty lines (our g_part rows) device-wide
        const unsigned old = __hip_atomic_fetch_add(&g_done, 1u, __ATOMIC_RELEASE,
                                                    __HIP_MEMORY_SCOPE_AGENT);
        const unsigned pos = old % NBLK;
        int f = (int)pos - (NBLK - NFIN);       // >=0 only for last NFIN arrivers
        if (f >= 0) {
            const unsigned goal = (old / NBLK + 1u) * NBLK;
            while (__hip_atomic_load(&g_done, __ATOMIC_RELAXED,
                                     __HIP_MEMORY_SCOPE_AGENT) < goal)
                __builtin_amdgcn_s_sleep(8);
            __threadfence();                    // acquire: invalidate stale lines
        }
        fidx = f;
    }
    __syncthreads();
    if (fidx < 0) return;

    // finalize slice [fidx*500, fidx*500+500): fold splits, add 0.5||t||^2
    const int tbase = fidx * TPERF;
    float local = 0.f;
    for (int k = tid; k < TPERF; k += TPB) {
        const int tt = tbase + k;
        float mn = FLT_MAX;
#pragma unroll
        for (int c = 0; c < SPLITS; ++c) mn = fminf(mn, g_part[c * N_TAR + tt]);
        const float x = tar[tt * 3 + 0];
        const float y = tar[tt * 3 + 1];
        const float z = tar[tt * 3 + 2];
        local += 0.5f * (x * x + y * y + z * z) + mn;
    }
    for (int off = 32; off > 0; off >>= 1)
        local += __shfl_down(local, off);
    if ((tid & 63) == 0) red[tid >> 6] = local;
    __syncthreads();
    if (tid == 0) {
        float s = 0.f;
#pragma unroll
        for (int w = 0; w < 8; ++w) s += red[w];
        atomicAdd(out, s);
    }
}

extern "C" void kernel_launch(void* const* d_in, const int* in_sizes, int n_in,
                              void* d_out, int out_size, void* d_ws, size_t ws_size,
                              hipStream_t stream) {
    const float* src = (const float*)d_in[0];  // [20000,3] fp32
    const float* tar = (const float*)d_in[1];  // [20000,3] fp32
    float* out = (float*)d_out;                // scalar fp32
    (void)d_ws; (void)ws_size;                 // ws untouched

    dim3 grid(TGRP, SPLITS);                   // 632 blocks, single dispatch
    nn_fused<<<grid, TPB, 0, stream>>>(src, tar, out);
}

// Round 8
// 80.029 us; speedup vs baseline: 1.1638x; 1.1638x over previous
//
#include <hip/hip_runtime.h>
#include <float.h>

#define N_SRC 20000
#define N_TAR 20000
#define TPB 512                    // 8 waves/block
#define SPLITS 13                  // source splits (grid.y)
#define PHASES 2                   // staging phases per split (reuse LDS)
#define TILES 26                   // 32-src tiles per phase (EVEN, for the pair loop)
#define SRC_PER_SPLIT 1539         // ceil(20000/13); 2*26*32=1664 >= 1539 coverage
#define TGRP 79                    // target-strip groups (grid.x); 79*8*32 = 20224 >= 20000
#define FBLOCKS ((N_TAR + 255) / 256)

typedef _Float16 half8 __attribute__((ext_vector_type(8)));
typedef float floatx16 __attribute__((ext_vector_type(16)));

// R8 geometry rationale (from R7's first-ever main-kernel counters:
// MfmaUtil 10.5%, VALUBusy 21.9%, Occupancy 22%, LDS_CONFLICT = 5 cyc/read):
//  - 79x13 = 1027 blocks ~= 4.01/CU (wave-limited 4 blocks/CU = 32 waves/CU):
//    balanced per-CU load + 8 waves/SIMD latency hiding (was ~2.5/CU, 3-vs-2
//    imbalance setting the kernel duration).
//  - LDS chunk swizzle SWZ kills the measured 5-extra-cycles-per-ds_read_b128
//    bank conflict (lane byte-stride 32 -> lanes l,l+4 shared a bank quad).
//  - g_part in a device global (NOT the poisoned ws; R6-validated), plain
//    stores only; cross-kernel visibility via dispatch boundary (R7 lesson:
//    per-block release fences cost ~15us in L2 writebacks).
__device__ float g_part[SPLITS * N_TAR];

// 16B-chunk slot relabeling inside each 1KB tile: XOR bit3 of the chunk index
// into bit0. Involution, applied identically at stage-write and frag-read, so
// it is correctness-neutral; spreads each 8-lane access group over 8 distinct
// bank quads (conflict-free for both the write and read patterns).
#define SWZ(n) ((n) ^ (((n) >> 3) & 1))

// DPP rotate-min within each 16-lane row (VALU pipe; HW-validated in R4).
#define ROTMIN(v, ctrl) \
    fminf(v, __int_as_float(__builtin_amdgcn_mov_dpp(__float_as_int(v), ctrl, 0xF, 0xF, false)))

// q(t,s) = 0.5||s||^2 - t.s, so 0.5*d2 = 0.5||t||^2 + q.
// One mfma_f32_32x32x16_f16 computes a 32x32 tile of q directly:
//   A row (target t): k0-8 = -t split-f16 cross terms, k9-10 = 1.0
//   B col (source s): k0-8 = s split-f16 terms,        k9-10 = split 0.5||s||^2
// split-f16 (hi/lo) keeps |q error| ~5e-6 (dropped lo*lo only).
// A layout: A[m=lane&31][k=(lane>>5)*8+j]; B[k=(lane>>5)*8+j][n=lane&31];
// C/D: col=lane&31, row=(reg&3)+8*(reg>>2)+4*(lane>>5)  [m74/m101].
__global__ __launch_bounds__(TPB) void nn_mfma(
    const float* __restrict__ src, const float* __restrict__ tar,
    float* __restrict__ out)
{
    if (blockIdx.x == 0 && blockIdx.y == 0 && threadIdx.x == 0) out[0] = 0.f;

    __shared__ alignas(16) _Float16 lds[TILES * 32 * 16];  // 26 KB -> 4 blocks/CU (wave-limited)

    const int tid  = threadIdx.x;
    const int lane = tid & 63;
    const int col  = lane & 31;
    const int hsel = (lane >> 5) & 1;
    const int wave = tid >> 6;

    // ---- build A fragment: this wave's 32 targets ----
    const int strip = blockIdx.x * 8 + wave;
    const int t = min(strip * 32 + col, N_TAR - 1);
    const float tx = tar[t * 3 + 0];
    const float ty = tar[t * 3 + 1];
    const float tz = tar[t * 3 + 2];
    const _Float16 txh = (_Float16)tx, tyh = (_Float16)ty, tzh = (_Float16)tz;
    const _Float16 txl = (_Float16)(tx - (float)txh);
    const _Float16 tyl = (_Float16)(ty - (float)tyh);
    const _Float16 tzl = (_Float16)(tz - (float)tzh);
    half8 a;
    if (hsel == 0)
        a = (half8){-txh, -tyh, -tzh, -txl, -tyl, -tzl, -txh, -tyh};
    else
        a = (half8){-tzh, (_Float16)1.f, (_Float16)1.f, 0, 0, 0, 0, 0};

    floatx16 m;
#pragma unroll
    for (int i = 0; i < 16; ++i) m[i] = FLT_MAX;
    const floatx16 zero = {};  // all-zero accumulator init
    const int rdc  = 2 * col + hsel;        // chunk this lane reads per tile
    const int foff = SWZ(rdc) * 8;          // element offset (swizzled)
    const int sbase0 = blockIdx.y * SRC_PER_SPLIT;

    for (int phase = 0; phase < PHASES; ++phase) {
        if (phase) __syncthreads();  // all waves done reading previous phase's LDS

        // ---- stage B fragments for this phase's 832 sources ----
        const int pbase = sbase0 + phase * (TILES * 32);
        for (int ls = tid; ls < TILES * 32; ls += TPB) {
            const int s = pbase + ls;
            half8 f0 = {0, 0, 0, 0, 0, 0, 0, 0};
            half8 f1 = {0, 0, 0, 0, 0, 0, 0, 0};
            if (s < N_SRC) {
                const float x = src[s * 3 + 0];
                const float y = src[s * 3 + 1];
                const float z = src[s * 3 + 2];
                const _Float16 xh = (_Float16)x, yh = (_Float16)y, zh = (_Float16)z;
                const _Float16 xl = (_Float16)(x - (float)xh);
                const _Float16 yl = (_Float16)(y - (float)yh);
                const _Float16 zl = (_Float16)(z - (float)zh);
                const float nrm = 0.5f * (x * x + y * y + z * z);
                const _Float16 nh = (_Float16)nrm;
                const _Float16 nl = (_Float16)(nrm - (float)nh);
                f0 = (half8){xh, yh, zh, xh, yh, zh, xl, yl};
                f1 = (half8){zl, nh, nl, 0, 0, 0, 0, 0};
            } else {
                f1 = (half8){0, (_Float16)30000.f, 0, 0, 0, 0, 0, 0}; // never the min
            }
            const int tile = ls >> 5;
            const int n0 = (ls & 31) * 2;
            *(half8*)&lds[tile * 512 + SWZ(n0) * 8]     = f0;
            *(half8*)&lds[tile * 512 + SWZ(n0 + 1) * 8] = f1;
        }

        __syncthreads();

        // ---- scan tiles in pairs: 2 ds_read_b128 + 2 mfma + 16 v_min3 / 2048 pairs ----
#pragma unroll 2
        for (int tp = 0; tp < TILES; tp += 2) {
            const half8 b0 = *(const half8*)&lds[tp * 512 + foff];
            const half8 b1 = *(const half8*)&lds[(tp + 1) * 512 + foff];
            const floatx16 d0 = __builtin_amdgcn_mfma_f32_32x32x16_f16(a, b0, zero, 0, 0, 0);
            const floatx16 d1 = __builtin_amdgcn_mfma_f32_32x32x16_f16(a, b1, zero, 0, 0, 0);
#pragma unroll
            for (int i = 0; i < 16; ++i)
                m[i] = fminf(fminf(d0[i], d1[i]), m[i]);  // -> v_min3_f32
        }
    }

    // ---- min over the 32 columns: 4x DPP row_ror (VALU) + 1 shfl_xor(16) ----
#pragma unroll
    for (int i = 0; i < 16; ++i) {
        float v = m[i];
        v = ROTMIN(v, 0x128);   // row_ror:8
        v = ROTMIN(v, 0x124);   // row_ror:4
        v = ROTMIN(v, 0x122);   // row_ror:2
        v = ROTMIN(v, 0x121);   // row_ror:1
        m[i] = fminf(v, __shfl_xor(v, 16));
    }
    if (col == 0) {
#pragma unroll
        for (int i = 0; i < 16; ++i) {
            const int row = (i & 3) + 8 * (i >> 2) + 4 * hsel;
            const int tt = min(strip * 32 + row, N_TAR - 1);
            g_part[blockIdx.y * N_TAR + tt] = m[i];  // clamp-dups write identical values
        }
    }
}

// combine the SPLITS mins per target, add 0.5||t||^2, reduce into out[0]
__global__ __launch_bounds__(256) void nn_finalize(
    const float* __restrict__ tar, float* __restrict__ out)
{
    const int t = blockIdx.x * 256 + threadIdx.x;
    float contrib = 0.f;
    if (t < N_TAR) {
        float m = FLT_MAX;
#pragma unroll
        for (int c = 0; c < SPLITS; ++c) m = fminf(m, g_part[c * N_TAR + t]);
        const float tx = tar[t * 3 + 0];
        const float ty = tar[t * 3 + 1];
        const float tz = tar[t * 3 + 2];
        contrib = 0.5f * (tx * tx + ty * ty + tz * tz) + m;
    }
    for (int off = 32; off > 0; off >>= 1)
        contrib += __shfl_down(contrib, off);
    __shared__ float red[4];
    if ((threadIdx.x & 63) == 0) red[threadIdx.x >> 6] = contrib;
    __syncthreads();
    if (threadIdx.x == 0) {
        float s = 0.f;
#pragma unroll
        for (int w = 0; w < 4; ++w) s += red[w];
        atomicAdd(out, s);
    }
}

extern "C" void kernel_launch(void* const* d_in, const int* in_sizes, int n_in,
                              void* d_out, int out_size, void* d_ws, size_t ws_size,
                              hipStream_t stream) {
    const float* src = (const float*)d_in[0];  // [20000,3] fp32
    const float* tar = (const float*)d_in[1];  // [20000,3] fp32
    float* out = (float*)d_out;                // scalar fp32
    (void)d_ws; (void)ws_size;                 // ws untouched

    dim3 grid1(TGRP, SPLITS);                  // 1027 blocks ~= 4.01/CU, balanced
    nn_mfma<<<grid1, TPB, 0, stream>>>(src, tar, out);
    nn_finalize<<<FBLOCKS, 256, 0, stream>>>(tar, out);
}

// Round 10
// 77.814 us; speedup vs baseline: 1.1970x; 1.0285x over previous
//
#include <hip/hip_runtime.h>
#include <float.h>

#define N_SRC 20000
#define N_TAR 20000
#define TPB 512                    // 8 waves/block
#define SPLITS 10                  // source splits (grid.y)
#define PHASES 2                   // staging phases per split (reuse 32 KB LDS)
#define TILES 32                   // 32-src tiles per phase; 10*2*32*32 = 20480 >= 20000
#define SRC_PER_SPLIT 2000         // 20000/10 exact
#define TGRP 79                    // target-strip groups (grid.x); 79*8*32 = 20224 >= 20000
#define FBLOCKS ((N_TAR + 255) / 256)

typedef _Float16 half8 __attribute__((ext_vector_type(8)));
typedef float floatx16 __attribute__((ext_vector_type(16)));

// R9 rationale (R7 counters: VALUBusy 22%, MfmaUtil 10.5% -> latency-stall-bound,
// ~4x above the ~5us pipe floor; R8 showed more occupancy alone doesn't fix it):
//  - staging trip count now EXACTLY 2 per thread (1024 src / 512 thr) -> fully
//    unrolled, both ~500-cyc global loads issue together instead of serially.
//  - T14 async-stage split: phase-1 source loads issue BEFORE phase-0 compute;
//    convert+ds_write happen after the barrier. Latency hides under MFMA+min3.
//  - 79x10 = 790 blocks <= 1024 residency slots (32KB LDS -> 4 blocks/CU,
//    wave-limited): one round, no straggler tail (R8 lesson: 1027 > 1024).
//  - everything else is R6-validated: linear LDS, DPP reduce, g_part device
//    global (NOT the poisoned ws), plain stores, two dispatches (R4/R7 lesson:
//    in-kernel cross-block handoff costs ~15us in fences/spin).
__device__ float g_part[SPLITS * N_TAR];

// DPP rotate-min within each 16-lane row (VALU pipe; HW-validated R4/R6).
#define ROTMIN(v, ctrl) \
    fminf(v, __int_as_float(__builtin_amdgcn_mov_dpp(__float_as_int(v), ctrl, 0xF, 0xF, false)))

struct SrcReg { float x, y, z; bool ok; };

__device__ __forceinline__ SrcReg load_src(const float* __restrict__ src, int s) {
    SrcReg r;
    r.ok = (s < N_SRC);
    const int sc = r.ok ? s : 0;
    r.x = src[sc * 3 + 0];
    r.y = src[sc * 3 + 1];
    r.z = src[sc * 3 + 2];
    return r;
}

__device__ __forceinline__ void cvt_store(_Float16* lds, int ls, SrcReg r) {
    half8 f0 = {0, 0, 0, 0, 0, 0, 0, 0};
    half8 f1;
    if (r.ok) {
        const _Float16 xh = (_Float16)r.x, yh = (_Float16)r.y, zh = (_Float16)r.z;
        const _Float16 xl = (_Float16)(r.x - (float)xh);
        const _Float16 yl = (_Float16)(r.y - (float)yh);
        const _Float16 zl = (_Float16)(r.z - (float)zh);
        const float nrm = 0.5f * (r.x * r.x + r.y * r.y + r.z * r.z);
        const _Float16 nh = (_Float16)nrm;
        const _Float16 nl = (_Float16)(nrm - (float)nh);
        f0 = (half8){xh, yh, zh, xh, yh, zh, xl, yl};
        f1 = (half8){zl, nh, nl, 0, 0, 0, 0, 0};
    } else {
        f1 = (half8){0, (_Float16)30000.f, 0, 0, 0, 0, 0, 0}; // never the min
    }
    *(half8*)&lds[ls * 16 + 0] = f0;
    *(half8*)&lds[ls * 16 + 8] = f1;
}

// q(t,s) = 0.5||s||^2 - t.s, so 0.5*d2 = 0.5||t||^2 + q.
// One mfma_f32_32x32x16_f16 computes a 32x32 tile of q directly:
//   A row (target t): k0-8 = -t split-f16 cross terms, k9-10 = 1.0
//   B col (source s): k0-8 = s split-f16 terms,        k9-10 = split 0.5||s||^2
// split-f16 (hi/lo) keeps |q error| ~5e-6 (dropped lo*lo only).
// A layout: A[m=lane&31][k=(lane>>5)*8+j]; B[k=(lane>>5)*8+j][n=lane&31];
// C/D: col=lane&31, row=(reg&3)+8*(reg>>2)+4*(lane>>5)  [m74/m101].
__global__ __launch_bounds__(TPB) void nn_mfma(
    const float* __restrict__ src, const float* __restrict__ tar,
    float* __restrict__ out)
{
    if (blockIdx.x == 0 && blockIdx.y == 0 && threadIdx.x == 0) out[0] = 0.f;

    __shared__ alignas(16) _Float16 lds[TILES * 32 * 16];  // 32 KB -> 4 blocks/CU

    const int tid  = threadIdx.x;
    const int lane = tid & 63;
    const int col  = lane & 31;
    const int hsel = (lane >> 5) & 1;
    const int wave = tid >> 6;

    const int sbase = blockIdx.y * SRC_PER_SPLIT;

    // ---- phase-0 staging: loads (2/thread, back-to-back) then convert+write ----
    SrcReg s0a = load_src(src, sbase + tid);
    SrcReg s0b = load_src(src, sbase + tid + TPB);

    // ---- build A fragment while phase-0 loads are in flight ----
    const int strip = blockIdx.x * 8 + wave;
    const int t = min(strip * 32 + col, N_TAR - 1);
    const float tx = tar[t * 3 + 0];
    const float ty = tar[t * 3 + 1];
    const float tz = tar[t * 3 + 2];
    const _Float16 txh = (_Float16)tx, tyh = (_Float16)ty, tzh = (_Float16)tz;
    const _Float16 txl = (_Float16)(tx - (float)txh);
    const _Float16 tyl = (_Float16)(ty - (float)tyh);
    const _Float16 tzl = (_Float16)(tz - (float)tzh);
    half8 a;
    if (hsel == 0)
        a = (half8){-txh, -tyh, -tzh, -txl, -tyl, -tzl, -txh, -tyh};
    else
        a = (half8){-tzh, (_Float16)1.f, (_Float16)1.f, 0, 0, 0, 0, 0};

    cvt_store(lds, tid, s0a);
    cvt_store(lds, tid + TPB, s0b);
    __syncthreads();

    // ---- T14: issue phase-1 loads NOW; latency hides under phase-0 compute ----
    SrcReg s1a = load_src(src, sbase + TILES * 32 + tid);
    SrcReg s1b = load_src(src, sbase + TILES * 32 + tid + TPB);

    floatx16 m;
#pragma unroll
    for (int i = 0; i < 16; ++i) m[i] = FLT_MAX;
    const floatx16 zero = {};  // all-zero accumulator init
    const int foff = col * 16 + hsel * 8;  // linear layout (R6-validated)

    // ---- phase-0 compute: 2 ds_read_b128 + 2 mfma + 16 v_min3 per tile pair ----
#pragma unroll 2
    for (int tp = 0; tp < TILES; tp += 2) {
        const half8 b0 = *(const half8*)&lds[tp * 512 + foff];
        const half8 b1 = *(const half8*)&lds[(tp + 1) * 512 + foff];
        const floatx16 d0 = __builtin_amdgcn_mfma_f32_32x32x16_f16(a, b0, zero, 0, 0, 0);
        const floatx16 d1 = __builtin_amdgcn_mfma_f32_32x32x16_f16(a, b1, zero, 0, 0, 0);
#pragma unroll
        for (int i = 0; i < 16; ++i)
            m[i] = fminf(fminf(d0[i], d1[i]), m[i]);  // -> v_min3_f32
    }

    __syncthreads();   // all waves done reading phase-0 LDS
    cvt_store(lds, tid, s1a);
    cvt_store(lds, tid + TPB, s1b);
    __syncthreads();

    // ---- phase-1 compute ----
#pragma unroll 2
    for (int tp = 0; tp < TILES; tp += 2) {
        const half8 b0 = *(const half8*)&lds[tp * 512 + foff];
        const half8 b1 = *(const half8*)&lds[(tp + 1) * 512 + foff];
        const floatx16 d0 = __builtin_amdgcn_mfma_f32_32x32x16_f16(a, b0, zero, 0, 0, 0);
        const floatx16 d1 = __builtin_amdgcn_mfma_f32_32x32x16_f16(a, b1, zero, 0, 0, 0);
#pragma unroll
        for (int i = 0; i < 16; ++i)
            m[i] = fminf(fminf(d0[i], d1[i]), m[i]);
    }

    // ---- min over the 32 columns: 4x DPP row_ror (VALU) + 1 shfl_xor(16) ----
#pragma unroll
    for (int i = 0; i < 16; ++i) {
        float v = m[i];
        v = ROTMIN(v, 0x128);   // row_ror:8
        v = ROTMIN(v, 0x124);   // row_ror:4
        v = ROTMIN(v, 0x122);   // row_ror:2
        v = ROTMIN(v, 0x121);   // row_ror:1
        m[i] = fminf(v, __shfl_xor(v, 16));
    }
    if (col == 0) {
#pragma unroll
        for (int i = 0; i < 16; ++i) {
            const int row = (i & 3) + 8 * (i >> 2) + 4 * hsel;
            const int tt = min(strip * 32 + row, N_TAR - 1);
            g_part[blockIdx.y * N_TAR + tt] = m[i];  // clamp-dups write identical values
        }
    }
}

// combine the SPLITS mins per target, add 0.5||t||^2, reduce into out[0]
__global__ __launch_bounds__(256) void nn_finalize(
    const float* __restrict__ tar, float* __restrict__ out)
{
    const int t = blockIdx.x * 256 + threadIdx.x;
    float contrib = 0.f;
    if (t < N_TAR) {
        float m = FLT_MAX;
#pragma unroll
        for (int c = 0; c < SPLITS; ++c) m = fminf(m, g_part[c * N_TAR + t]);
        const float tx = tar[t * 3 + 0];
        const float ty = tar[t * 3 + 1];
        const float tz = tar[t * 3 + 2];
        contrib = 0.5f * (tx * tx + ty * ty + tz * tz) + m;
    }
    for (int off = 32; off > 0; off >>= 1)
        contrib += __shfl_down(contrib, off);
    __shared__ float red[4];
    if ((threadIdx.x & 63) == 0) red[threadIdx.x >> 6] = contrib;
    __syncthreads();
    if (threadIdx.x == 0) {
        float s = 0.f;
#pragma unroll
        for (int w = 0; w < 4; ++w) s += red[w];
        atomicAdd(out, s);
    }
}

extern "C" void kernel_launch(void* const* d_in, const int* in_sizes, int n_in,
                              void* d_out, int out_size, void* d_ws, size_t ws_size,
                              hipStream_t stream) {
    const float* src = (const float*)d_in[0];  // [20000,3] fp32
    const float* tar = (const float*)d_in[1];  // [20000,3] fp32
    float* out = (float*)d_out;                // scalar fp32
    (void)d_ws; (void)ws_size;                 // ws untouched

    dim3 grid1(TGRP, SPLITS);                  // 790 blocks, one residency round
    nn_mfma<<<grid1, TPB, 0, stream>>>(src, tar, out);
    nn_finalize<<<FBLOCKS, 256, 0, stream>>>(tar, out);
}